// Round 7
// baseline (1660.301 us; speedup 1.0000x reference)
//
#include <hip/hip_runtime.h>
#include <math.h>

typedef _Float16 f16;
typedef __attribute__((ext_vector_type(8))) _Float16 half8;
typedef __attribute__((ext_vector_type(4))) float float4v;

// ---------------- helpers ----------------
__device__ __forceinline__ float fast_sigmoid(float x) { return 1.0f / (1.0f + __expf(-x)); }
__device__ __forceinline__ float fast_tanh(float x) {
    float a = fabsf(x);
    float e = __expf(-2.0f * a);
    float t = (1.0f - e) / (1.0f + e);
    return copysignf(t, x);
}

// ---------------- prep kernels ----------------
// Gate-permuted fp16 weights: Bp[col'][k], col' = dg*64 + q*16 + dl
// original gate-row j = q*128 + dg*16 + dl. k<Kih -> Wih[j][k], else Whh[j][k-Kih].
__global__ void packb_kernel(const float* __restrict__ Wih, int Kih,
                             const float* __restrict__ Whh, int K,
                             const float* __restrict__ bih, const float* __restrict__ bhh,
                             f16* __restrict__ Bp, float* __restrict__ bp) {
    int t = blockIdx.x * blockDim.x + threadIdx.x;
    if (t >= (K << 9)) return;
    int colp = t / K;
    int k = t - colp * K;
    int dg = colp >> 6, q = (colp >> 4) & 3, dl = colp & 15;
    int j = q * 128 + dg * 16 + dl;
    float v = (k < Kih) ? Wih[j * Kih + k] : Whh[j * (K - Kih) + (k - Kih)];
    Bp[t] = (f16)v;
    if (k == 0) bp[colp] = bih[j] + bhh[j];
}

__global__ void feat0_kernel(const float* __restrict__ features, const float* __restrict__ W_in,
                             const float* __restrict__ b_in, f16* __restrict__ feat, int n) {
    int t = blockIdx.x * blockDim.x + threadIdx.x;
    if (t >= n * 128) return;
    int node = t >> 7;
    int d = t & 127;
    float s = b_in[d];
#pragma unroll
    for (int k = 0; k < 6; ++k) s += features[node * 6 + k] * W_in[k * 128 + d];
    feat[t] = (f16)fmaxf(s, 0.0f);
}

__global__ void hist_kernel(const int* __restrict__ dst, int* __restrict__ cnt, int e) {
    int t = blockIdx.x * blockDim.x + threadIdx.x;
    if (t < e) atomicAdd(&cnt[dst[t]], 1);
}

// single-block scan, coalesced: rounds of 1024 coalesced loads + block-wide scan
__global__ void scan_kernel(const int* __restrict__ cnt, int* __restrict__ off,
                            int* __restrict__ cur, float* __restrict__ recip, int n) {
    __shared__ int wsum[16];
    __shared__ int stot;
    int t = threadIdx.x;       // 1024
    int lane = t & 63, wv = t >> 6;
    int R = 0;                 // running base (uniform across threads)
    int rounds = (n + 1023) >> 10;
    for (int i = 0; i < rounds; ++i) {
        int idx = (i << 10) + t;
        int v = (idx < n) ? cnt[idx] : 0;
        // wave inclusive scan
        int s = v;
#pragma unroll
        for (int o = 1; o < 64; o <<= 1) {
            int u = __shfl_up(s, o, 64);
            if (lane >= o) s += u;
        }
        if (lane == 63) wsum[wv] = s;
        __syncthreads();
        if (t == 0) {
            int a = 0;
#pragma unroll
            for (int j = 0; j < 16; ++j) { int x = wsum[j]; wsum[j] = a; a += x; }
            stot = a;
        }
        __syncthreads();
        int excl = R + wsum[wv] + s - v;
        if (idx < n) {
            off[idx] = excl; cur[idx] = excl;
            recip[idx] = (v > 0) ? 1.0f / (float)v : 0.0f;
        }
        R += stot;
        __syncthreads();   // wsum/stot reuse next round
    }
    if (t == 0) off[n] = R;
}

__global__ void scatter_kernel(const int* __restrict__ src, const int* __restrict__ dst,
                               int* __restrict__ cur, int* __restrict__ esrc, int e) {
    int t = blockIdx.x * blockDim.x + threadIdx.x;
    if (t >= e) return;
    int d = dst[t];
    int p = atomicAdd(&cur[d], 1);
    esrc[p] = src[t];
}

// mean aggregation: 16 lanes (8 halves each) per node, 16 nodes/block,
// fp32 accum, edge loop unrolled x8 for MLP.
__global__ __launch_bounds__(256, 6) void agg_kernel(
    const f16* __restrict__ feat, const int* __restrict__ off,
    const int* __restrict__ esrc, const float* __restrict__ recip,
    f16* __restrict__ agg, int n) {
    int slot = threadIdx.x >> 4;
    int lane = threadIdx.x & 15;
    int v = blockIdx.x * 16 + slot;
    if (v >= n) return;
    int e0 = off[v], e1 = off[v + 1];
    float a[8];
#pragma unroll
    for (int j = 0; j < 8; ++j) a[j] = 0.0f;
    int e = e0;
    for (; e + 8 <= e1; e += 8) {
        int ss[8];
#pragma unroll
        for (int u = 0; u < 8; ++u) ss[u] = esrc[e + u];
        half8 vv[8];
#pragma unroll
        for (int u = 0; u < 8; ++u)
            vv[u] = *(const half8*)&feat[(size_t)ss[u] * 128 + lane * 8];
#pragma unroll
        for (int u = 0; u < 8; ++u)
#pragma unroll
            for (int j = 0; j < 8; ++j) a[j] += (float)vv[u][j];
    }
    for (; e < e1; ++e) {
        int s = esrc[e];
        half8 v0 = *(const half8*)&feat[(size_t)s * 128 + lane * 8];
#pragma unroll
        for (int j = 0; j < 8; ++j) a[j] += (float)v0[j];
    }
    float r = recip[v];
    half8 o;
#pragma unroll
    for (int j = 0; j < 8; ++j) o[j] = (f16)(a[j] * r);
    *(half8*)&agg[(size_t)v * 128 + lane * 8] = o;
}

// ---------------- MFMA GEMM + LSTM cell (one layer per launch) ----------------
// No LDS, no barriers. 256-thread blocks = 4 independent waves.
// Global wave gw: row block rb = gw>>2 (64 rows), col group cg = gw&3 (128 cols =
// tiles mb..mb+7, mb = 8*cg). Per kt: 32 MFMA; b/a frags loaded DIRECT global->reg
// (each B element consumed by exactly one wave — LDS staging bought nothing).
// Software pipeline: issue kt+1's 12 loads, compute kt (auto vmcnt(12) wait).
#define BM 64

template <int KT>
__global__ __launch_bounds__(256, 2) void gemm_lstm(
    const f16* __restrict__ A0, const f16* __restrict__ A1, const f16* __restrict__ A2,
    const f16* __restrict__ Bp, const float* __restrict__ bp,
    float* __restrict__ c, f16* __restrict__ h_out, int nrows) {
    constexpr int K = KT * 32;
    const int w = threadIdx.x >> 6;
    const int lane = threadIdx.x & 63;
    const int gw = blockIdx.x * 4 + w;
    const int rb = gw >> 2;
    const int cg = gw & 3;
    const int row0 = rb * BM;
    const int mb = cg * 8;
    const int dl = lane & 15;
    const int quad = lane >> 4;

    float4v acc[4][8];  // [row-tile rt][j = hh*4 + q]
#pragma unroll
    for (int j = 0; j < 8; ++j) {
        float b = bp[(mb + j) * 16 + dl];
#pragma unroll
        for (int rt = 0; rt < 4; ++rt) {
            acc[rt][j][0] = b; acc[rt][j][1] = b; acc[rt][j][2] = b; acc[rt][j][3] = b;
        }
    }

    // lane-fixed base: tile j adds j*16*K, kt adds kt*32
    const f16* bbase = Bp + (size_t)(mb * 16 + dl) * K + (quad << 3);
    const f16* arow0 = nullptr;  // per-part row base recomputed

    half8 a_cur[4], b_cur[8], a_nxt[4], b_nxt[8];
    // prefetch kt = 0 (part 0 = A0)
#pragma unroll
    for (int j = 0; j < 8; ++j)
        b_cur[j] = *(const half8*)&bbase[(size_t)j * 16 * K];
#pragma unroll
    for (int rt = 0; rt < 4; ++rt)
        a_cur[rt] = *(const half8*)&A0[(size_t)(row0 + rt * 16 + dl) * 128 + (quad << 3)];

#pragma unroll
    for (int kt = 0; kt < KT; ++kt) {
        if (kt + 1 < KT) {
            const int pi = (kt + 1) >> 2;
            const f16* Ap = A0;
            if (pi == 1) Ap = A1;
            if (pi == 2) Ap = A2;
            const int kk = ((kt + 1) & 3) * 32;
#pragma unroll
            for (int j = 0; j < 8; ++j)
                b_nxt[j] = *(const half8*)&bbase[(size_t)j * 16 * K + (kt + 1) * 32];
#pragma unroll
            for (int rt = 0; rt < 4; ++rt)
                a_nxt[rt] = *(const half8*)&Ap[(size_t)(row0 + rt * 16 + dl) * 128 + kk + (quad << 3)];
        }
#pragma unroll
        for (int j = 0; j < 8; ++j)
#pragma unroll
            for (int rt = 0; rt < 4; ++rt)
                acc[rt][j] = __builtin_amdgcn_mfma_f32_16x16x32_f16(a_cur[rt], b_cur[j], acc[rt][j], 0, 0, 0);
        if (kt + 1 < KT) {
#pragma unroll
            for (int j = 0; j < 8; ++j) b_cur[j] = b_nxt[j];
#pragma unroll
            for (int rt = 0; rt < 4; ++rt) a_cur[rt] = a_nxt[rt];
        }
    }

    // epilogue: tile j = hh*4+q -> dim group dg = cg*2 + hh, gate q; lane-local i,f,g,o
#pragma unroll
    for (int hh = 0; hh < 2; ++hh) {
        const int d = (cg * 2 + hh) * 16 + dl;
#pragma unroll
        for (int rt = 0; rt < 4; ++rt) {
#pragma unroll
            for (int r = 0; r < 4; ++r) {
                int n = row0 + rt * 16 + (quad << 2) + r;
                if (n < nrows) {
                    float ig = fast_sigmoid(acc[rt][(hh << 2) + 0][r]);
                    float fg = fast_sigmoid(acc[rt][(hh << 2) + 1][r]);
                    float gg = fast_tanh(acc[rt][(hh << 2) + 2][r]);
                    float og = fast_sigmoid(acc[rt][(hh << 2) + 3][r]);
                    float cold = c[(size_t)n * 128 + d];
                    float cn = fg * cold + ig * gg;
                    c[(size_t)n * 128 + d] = cn;
                    h_out[(size_t)n * 128 + d] = (f16)(og * fast_tanh(cn));
                }
            }
        }
    }
}

// ---------------- output projection ----------------
__global__ void out_kernel(const f16* __restrict__ h2, const float* __restrict__ Wout,
                           const float* __restrict__ bout, float* __restrict__ out) {
    int n = blockIdx.x;
    int l = threadIdx.x;  // 0..63
    float v = (float)h2[(size_t)n * 128 + l] * Wout[l] +
              (float)h2[(size_t)n * 128 + 64 + l] * Wout[64 + l];
#pragma unroll
    for (int o = 32; o > 0; o >>= 1) v += __shfl_down(v, o, 64);
    if (l == 0) out[n] = v + bout[0];
}

// ---------------- launch ----------------
extern "C" void kernel_launch(void* const* d_in, const int* in_sizes, int n_in,
                              void* d_out, int out_size, void* d_ws, size_t ws_size,
                              hipStream_t stream) {
    const float* features = (const float*)d_in[0];
    const int*   src      = (const int*)d_in[1];
    const int*   dst      = (const int*)d_in[2];
    const float* W_in     = (const float*)d_in[3];
    const float* b_in     = (const float*)d_in[4];
    const float* Wih0     = (const float*)d_in[5];
    const float* Wih_rest = (const float*)d_in[6];
    const float* Whh      = (const float*)d_in[7];
    const float* bih      = (const float*)d_in[8];
    const float* bhh      = (const float*)d_in[9];
    const float* W_out    = (const float*)d_in[10];
    const float* b_out    = (const float*)d_in[11];
    float* out = (float*)d_out;

    const int N = in_sizes[0] / 6;  // 20000
    const int E = in_sizes[1];      // 640000
    const int NP = N + BM;          // padded rows: A-frag loads never OOB

    char* ws = (char*)d_ws;
    size_t pos = 0;
    auto alloc = [&](size_t bytes) -> void* {
        void* p = ws + pos;
        pos = (pos + bytes + 255) & ~(size_t)255;
        return p;
    };
    const size_t hrow = 128;
    const size_t hbytes = (size_t)NP * hrow * sizeof(f16);
    const size_t cbytes = (size_t)NP * hrow * sizeof(float);
    f16* feath = (f16*)alloc(hbytes);
    f16* aggh  = (f16*)alloc(hbytes);
    f16* hblk  = (f16*)alloc(6 * hbytes);   // ping-pong: A-set then B-set
    f16* hA[3], * hB[3];
    for (int l = 0; l < 3; ++l) {
        hA[l] = hblk + (size_t)l * NP * hrow;
        hB[l] = hblk + (size_t)(l + 3) * NP * hrow;
    }
    float* cblk = (float*)alloc(3 * cbytes);
    float* c0 = cblk + 0 * (size_t)NP * hrow;
    float* c1 = cblk + 1 * (size_t)NP * hrow;
    float* c2 = cblk + 2 * (size_t)NP * hrow;
    f16* Bp0 = (f16*)alloc((size_t)512 * 384 * sizeof(f16));
    f16* Bp1 = (f16*)alloc((size_t)512 * 256 * sizeof(f16));
    f16* Bp2 = (f16*)alloc((size_t)512 * 256 * sizeof(f16));
    float* bp0 = (float*)alloc(512 * sizeof(float));
    float* bp1 = (float*)alloc(512 * sizeof(float));
    float* bp2 = (float*)alloc(512 * sizeof(float));
    int*   cnt   = (int*)alloc((size_t)N * 4);
    int*   offs  = (int*)alloc((size_t)(N + 1) * 4);
    int*   cur   = (int*)alloc((size_t)N * 4);
    int*   esrc  = (int*)alloc((size_t)E * 4);
    float* recip = (float*)alloc((size_t)N * 4);

    hipMemsetAsync(hblk, 0, 6 * hbytes, stream);
    hipMemsetAsync(cblk, 0, 3 * cbytes, stream);
    hipMemsetAsync(cnt, 0, (size_t)N * 4, stream);

    packb_kernel<<<(512 * 384 + 255) / 256, 256, 0, stream>>>(
        Wih0, 256, Whh, 384, bih, bhh, Bp0, bp0);
    packb_kernel<<<(512 * 256 + 255) / 256, 256, 0, stream>>>(
        Wih_rest, 128, Whh + 512 * 128, 256, bih + 512, bhh + 512, Bp1, bp1);
    packb_kernel<<<(512 * 256 + 255) / 256, 256, 0, stream>>>(
        Wih_rest + 512 * 128, 128, Whh + 2 * 512 * 128, 256, bih + 1024, bhh + 1024, Bp2, bp2);

    feat0_kernel<<<(N * 128 + 255) / 256, 256, 0, stream>>>(features, W_in, b_in, feath, N);
    hist_kernel<<<(E + 255) / 256, 256, 0, stream>>>(dst, cnt, E);
    scan_kernel<<<1, 1024, 0, stream>>>(cnt, offs, cur, recip, N);
    scatter_kernel<<<(E + 255) / 256, 256, 0, stream>>>(src, dst, cur, esrc, E);

    const int nrb = (N + BM - 1) / BM;              // 313 row blocks
    const int gx = nrb;                              // 4 waves/block = 4 col groups
    const int gagg = (N + 15) / 16;
    const f16* featcur = feath;
    f16 *r0 = hA[0], *r1 = hA[1], *r2 = hA[2];   // read (old state)
    f16 *w0 = hB[0], *w1 = hB[1], *w2 = hB[2];   // write (new state)
    for (int step = 0; step < 11; ++step) {
        agg_kernel<<<gagg, 256, 0, stream>>>(featcur, offs, esrc, recip, aggh, N);
        gemm_lstm<12><<<gx, 256, 0, stream>>>(aggh, featcur, r0, Bp0, bp0, c0, w0, N);
        gemm_lstm<8><<<gx, 256, 0, stream>>>(w0, r1, nullptr, Bp1, bp1, c1, w1, N);
        gemm_lstm<8><<<gx, 256, 0, stream>>>(w1, r2, nullptr, Bp2, bp2, c2, w2, N);
        featcur = w2;
        f16* t;
        t = r0; r0 = w0; w0 = t;
        t = r1; r1 = w1; w1 = t;
        t = r2; r2 = w2; w2 = t;
    }
    out_kernel<<<N, 64, 0, stream>>>((const f16*)featcur, W_out, b_out, out);
}

// Round 8
// 1093.853 us; speedup vs baseline: 1.5178x; 1.5178x over previous
//
#include <hip/hip_runtime.h>
#include <math.h>

typedef _Float16 f16;
typedef __attribute__((ext_vector_type(8))) _Float16 half8;
typedef __attribute__((ext_vector_type(4))) float float4v;

// ---------------- helpers ----------------
__device__ __forceinline__ float fast_sigmoid(float x) { return 1.0f / (1.0f + __expf(-x)); }
__device__ __forceinline__ float fast_tanh(float x) {
    float a = fabsf(x);
    float e = __expf(-2.0f * a);
    float t = (1.0f - e) / (1.0f + e);
    return copysignf(t, x);
}

// async global->LDS, 16B per lane. LDS dest = wave-uniform base + lane*16.
__device__ __forceinline__ void async_copy16(const void* gsrc, void* ldst) {
    __builtin_amdgcn_global_load_lds(
        (const __attribute__((address_space(1))) void*)gsrc,
        (__attribute__((address_space(3))) void*)ldst,
        16, 0, 0);
}

// ---------------- prep kernels ----------------
// Gate-permuted fp16 weights: Bp[col'][k], col' = dg*64 + q*16 + dl
// original gate-row j = q*128 + dg*16 + dl. k<Kih -> Wih[j][k], else Whh[j][k-Kih].
__global__ void packb_kernel(const float* __restrict__ Wih, int Kih,
                             const float* __restrict__ Whh, int K,
                             const float* __restrict__ bih, const float* __restrict__ bhh,
                             f16* __restrict__ Bp, float* __restrict__ bp) {
    int t = blockIdx.x * blockDim.x + threadIdx.x;
    if (t >= (K << 9)) return;
    int colp = t / K;
    int k = t - colp * K;
    int dg = colp >> 6, q = (colp >> 4) & 3, dl = colp & 15;
    int j = q * 128 + dg * 16 + dl;
    float v = (k < Kih) ? Wih[j * Kih + k] : Whh[j * (K - Kih) + (k - Kih)];
    Bp[t] = (f16)v;
    if (k == 0) bp[colp] = bih[j] + bhh[j];
}

__global__ void feat0_kernel(const float* __restrict__ features, const float* __restrict__ W_in,
                             const float* __restrict__ b_in, f16* __restrict__ feat, int n) {
    int t = blockIdx.x * blockDim.x + threadIdx.x;
    if (t >= n * 128) return;
    int node = t >> 7;
    int d = t & 127;
    float s = b_in[d];
#pragma unroll
    for (int k = 0; k < 6; ++k) s += features[node * 6 + k] * W_in[k * 128 + d];
    feat[t] = (f16)fmaxf(s, 0.0f);
}

__global__ void hist_kernel(const int* __restrict__ dst, int* __restrict__ cnt, int e) {
    int t = blockIdx.x * blockDim.x + threadIdx.x;
    if (t < e) atomicAdd(&cnt[dst[t]], 1);
}

// single-block scan, coalesced: rounds of 1024 coalesced loads + block-wide scan
__global__ void scan_kernel(const int* __restrict__ cnt, int* __restrict__ off,
                            int* __restrict__ cur, float* __restrict__ recip, int n) {
    __shared__ int wsum[16];
    __shared__ int stot;
    int t = threadIdx.x;       // 1024
    int lane = t & 63, wv = t >> 6;
    int R = 0;                 // running base (uniform across threads)
    int rounds = (n + 1023) >> 10;
    for (int i = 0; i < rounds; ++i) {
        int idx = (i << 10) + t;
        int v = (idx < n) ? cnt[idx] : 0;
        int s = v;
#pragma unroll
        for (int o = 1; o < 64; o <<= 1) {
            int u = __shfl_up(s, o, 64);
            if (lane >= o) s += u;
        }
        if (lane == 63) wsum[wv] = s;
        __syncthreads();
        if (t == 0) {
            int a = 0;
#pragma unroll
            for (int j = 0; j < 16; ++j) { int x = wsum[j]; wsum[j] = a; a += x; }
            stot = a;
        }
        __syncthreads();
        int excl = R + wsum[wv] + s - v;
        if (idx < n) {
            off[idx] = excl; cur[idx] = excl;
            recip[idx] = (v > 0) ? 1.0f / (float)v : 0.0f;
        }
        R += stot;
        __syncthreads();
    }
    if (t == 0) off[n] = R;
}

__global__ void scatter_kernel(const int* __restrict__ src, const int* __restrict__ dst,
                               int* __restrict__ cur, int* __restrict__ esrc, int e) {
    int t = blockIdx.x * blockDim.x + threadIdx.x;
    if (t >= e) return;
    int d = dst[t];
    int p = atomicAdd(&cur[d], 1);
    esrc[p] = src[t];
}

// mean aggregation: 16 lanes (8 halves each) per node, 16 nodes/block,
// fp32 accum, edge loop unrolled x8 for MLP.
__global__ __launch_bounds__(256, 6) void agg_kernel(
    const f16* __restrict__ feat, const int* __restrict__ off,
    const int* __restrict__ esrc, const float* __restrict__ recip,
    f16* __restrict__ agg, int n) {
    int slot = threadIdx.x >> 4;
    int lane = threadIdx.x & 15;
    int v = blockIdx.x * 16 + slot;
    if (v >= n) return;
    int e0 = off[v], e1 = off[v + 1];
    float a[8];
#pragma unroll
    for (int j = 0; j < 8; ++j) a[j] = 0.0f;
    int e = e0;
    for (; e + 8 <= e1; e += 8) {
        int ss[8];
#pragma unroll
        for (int u = 0; u < 8; ++u) ss[u] = esrc[e + u];
        half8 vv[8];
#pragma unroll
        for (int u = 0; u < 8; ++u)
            vv[u] = *(const half8*)&feat[(size_t)ss[u] * 128 + lane * 8];
#pragma unroll
        for (int u = 0; u < 8; ++u)
#pragma unroll
            for (int j = 0; j < 8; ++j) a[j] += (float)vv[u][j];
    }
    for (; e < e1; ++e) {
        int s = esrc[e];
        half8 v0 = *(const half8*)&feat[(size_t)s * 128 + lane * 8];
#pragma unroll
        for (int j = 0; j < 8; ++j) a[j] += (float)v0[j];
    }
    float r = recip[v];
    half8 o;
#pragma unroll
    for (int j = 0; j < 8; ++j) o[j] = (f16)(a[j] * r);
    *(half8*)&agg[(size_t)v * 128 + lane * 8] = o;
}

// ---------------- fused MFMA GEMM + LSTM cell (R3 structure + swizzle) ----------------
// Block: 256 threads = 4 waves, tile 64 rows x 256 cols (blockIdx.y = col half).
// Wave w: 64 rows x 64 cols = 4x4 grid of 16x16x32 f16 MFMA (tiles w*4..w*4+3).
// LDS: As 4 KB (cross-wave shared rows) + Bs 16 KB; staged via global_load_lds.
// Bank-conflict-free swizzle: k-group g of row r stored at slot g ^ ((r>>1)&3)
// -> every 16-lane read phase hits each bank exactly 2x (2-way = free, m136).
#define BM 64

template <int PARTS>
__global__ __launch_bounds__(256, 3) void gemm_lstm(
    const f16* __restrict__ A0, const f16* __restrict__ A1, const f16* __restrict__ A2,
    const f16* __restrict__ Bp, const float* __restrict__ bp,
    float* __restrict__ c, f16* __restrict__ h_out, int nrows) {
    constexpr int K = PARTS * 128;
    __shared__ f16 As[64 * 32];    // [row][slot*8] 4 KB
    __shared__ f16 Bs[256 * 32];   // [col'][slot*8] 16 KB

    const int tid = threadIdx.x;
    const int w = tid >> 6;      // wave 0..3
    const int lane = tid & 63;
    const int dl = lane & 15;
    const int quad = lane >> 4;
    const int row0 = blockIdx.x * BM;
    const int cb = blockIdx.y;   // 0..1

    float4v acc[4][4];  // [row-tile rt][gate q]
#pragma unroll
    for (int q = 0; q < 4; ++q) {
        float b = bp[cb * 256 + w * 64 + q * 16 + dl];
#pragma unroll
        for (int rt = 0; rt < 4; ++rt) {
            acc[rt][q][0] = b; acc[rt][q][1] = b; acc[rt][q][2] = b; acc[rt][q][3] = b;
        }
    }

    const int srow = lane >> 2;       // staging row within 16-row group
    const int sj = lane & 3;          // staging slot
    // swizzled global k-group for this staging lane
    const int sg = sj ^ ((srow >> 1) & 3);
    // swizzled slot offset for fragment reads (halves)
    const int rslot = (quad ^ ((dl >> 1) & 3)) << 3;

    for (int kt = 0; kt < PARTS * 4; ++kt) {
        const f16* Ap = A0;
        const int pi = kt >> 2;
        if (PARTS >= 2 && pi == 1) Ap = A1;
        if (PARTS >= 3 && pi == 2) Ap = A2;
        const int kk = (kt & 3) * 32;   // A-part-local k offset

        __syncthreads();  // previous iteration's ds_reads complete
        // stage A: wave w covers rows w*16..+15 (slot sj holds k-group sg)
        async_copy16(&Ap[(size_t)(row0 + w * 16 + srow) * 128 + kk + (sg << 3)],
                     (f16*)As + w * 512);
        // stage B: 4 calls/wave, chunk m = i*4 + w; B k-offset is GLOBAL kt*32
        const f16* Bbase = Bp + (size_t)(cb * 256) * K + kt * 32;
#pragma unroll
        for (int i = 0; i < 4; ++i) {
            int m = i * 4 + w;
            async_copy16(&Bbase[(size_t)(m * 16 + srow) * K + (sg << 3)],
                         (f16*)Bs + m * 512);
        }
        __syncthreads();  // vmcnt(0) drain: staging visible

        half8 a[4], b[4];
#pragma unroll
        for (int rt = 0; rt < 4; ++rt)
            a[rt] = *(const half8*)&As[(rt * 16 + dl) * 32 + rslot];
#pragma unroll
        for (int q = 0; q < 4; ++q)
            b[q] = *(const half8*)&Bs[((w * 4 + q) * 16 + dl) * 32 + rslot];
#pragma unroll
        for (int rt = 0; rt < 4; ++rt)
#pragma unroll
            for (int q = 0; q < 4; ++q)
                acc[rt][q] = __builtin_amdgcn_mfma_f32_16x16x32_f16(a[rt], b[q], acc[rt][q], 0, 0, 0);
    }

    // epilogue: lane owns dim d, rows rt*16 + quad*4 + r, all 4 gates in acc[rt][*]
    const int d = cb * 64 + w * 16 + dl;
#pragma unroll
    for (int rt = 0; rt < 4; ++rt) {
#pragma unroll
        for (int r = 0; r < 4; ++r) {
            int n = row0 + rt * 16 + (quad << 2) + r;
            if (n < nrows) {
                float ig = fast_sigmoid(acc[rt][0][r]);
                float fg = fast_sigmoid(acc[rt][1][r]);
                float gg = fast_tanh(acc[rt][2][r]);
                float og = fast_sigmoid(acc[rt][3][r]);
                float cold = c[(size_t)n * 128 + d];
                float cn = fg * cold + ig * gg;
                c[(size_t)n * 128 + d] = cn;
                h_out[(size_t)n * 128 + d] = (f16)(og * fast_tanh(cn));
            }
        }
    }
}

// ---------------- output projection ----------------
__global__ void out_kernel(const f16* __restrict__ h2, const float* __restrict__ Wout,
                           const float* __restrict__ bout, float* __restrict__ out) {
    int n = blockIdx.x;
    int l = threadIdx.x;  // 0..63
    float v = (float)h2[(size_t)n * 128 + l] * Wout[l] +
              (float)h2[(size_t)n * 128 + 64 + l] * Wout[64 + l];
#pragma unroll
    for (int o = 32; o > 0; o >>= 1) v += __shfl_down(v, o, 64);
    if (l == 0) out[n] = v + bout[0];
}

// ---------------- launch ----------------
extern "C" void kernel_launch(void* const* d_in, const int* in_sizes, int n_in,
                              void* d_out, int out_size, void* d_ws, size_t ws_size,
                              hipStream_t stream) {
    const float* features = (const float*)d_in[0];
    const int*   src      = (const int*)d_in[1];
    const int*   dst      = (const int*)d_in[2];
    const float* W_in     = (const float*)d_in[3];
    const float* b_in     = (const float*)d_in[4];
    const float* Wih0     = (const float*)d_in[5];
    const float* Wih_rest = (const float*)d_in[6];
    const float* Whh      = (const float*)d_in[7];
    const float* bih      = (const float*)d_in[8];
    const float* bhh      = (const float*)d_in[9];
    const float* W_out    = (const float*)d_in[10];
    const float* b_out    = (const float*)d_in[11];
    float* out = (float*)d_out;

    const int N = in_sizes[0] / 6;  // 20000
    const int E = in_sizes[1];      // 640000
    const int NP = N + BM;          // padded rows: staging never reads unmapped mem

    char* ws = (char*)d_ws;
    size_t pos = 0;
    auto alloc = [&](size_t bytes) -> void* {
        void* p = ws + pos;
        pos = (pos + bytes + 255) & ~(size_t)255;
        return p;
    };
    const size_t hrow = 128;
    const size_t hbytes = (size_t)NP * hrow * sizeof(f16);
    const size_t cbytes = (size_t)NP * hrow * sizeof(float);
    f16* feath = (f16*)alloc(hbytes);
    f16* aggh  = (f16*)alloc(hbytes);
    f16* hblk  = (f16*)alloc(6 * hbytes);   // ping-pong: A-set then B-set
    f16* hA[3], * hB[3];
    for (int l = 0; l < 3; ++l) {
        hA[l] = hblk + (size_t)l * NP * hrow;
        hB[l] = hblk + (size_t)(l + 3) * NP * hrow;
    }
    float* cblk = (float*)alloc(3 * cbytes);
    float* c0 = cblk + 0 * (size_t)NP * hrow;
    float* c1 = cblk + 1 * (size_t)NP * hrow;
    float* c2 = cblk + 2 * (size_t)NP * hrow;
    f16* Bp0 = (f16*)alloc((size_t)512 * 384 * sizeof(f16));
    f16* Bp1 = (f16*)alloc((size_t)512 * 256 * sizeof(f16));
    f16* Bp2 = (f16*)alloc((size_t)512 * 256 * sizeof(f16));
    float* bp0 = (float*)alloc(512 * sizeof(float));
    float* bp1 = (float*)alloc(512 * sizeof(float));
    float* bp2 = (float*)alloc(512 * sizeof(float));
    int*   cnt   = (int*)alloc((size_t)N * 4);
    int*   offs  = (int*)alloc((size_t)(N + 1) * 4);
    int*   cur   = (int*)alloc((size_t)N * 4);
    int*   esrc  = (int*)alloc((size_t)E * 4);
    float* recip = (float*)alloc((size_t)N * 4);

    hipMemsetAsync(hblk, 0, 6 * hbytes, stream);
    hipMemsetAsync(cblk, 0, 3 * cbytes, stream);
    hipMemsetAsync(cnt, 0, (size_t)N * 4, stream);

    packb_kernel<<<(512 * 384 + 255) / 256, 256, 0, stream>>>(
        Wih0, 256, Whh, 384, bih, bhh, Bp0, bp0);
    packb_kernel<<<(512 * 256 + 255) / 256, 256, 0, stream>>>(
        Wih_rest, 128, Whh + 512 * 128, 256, bih + 512, bhh + 512, Bp1, bp1);
    packb_kernel<<<(512 * 256 + 255) / 256, 256, 0, stream>>>(
        Wih_rest + 512 * 128, 128, Whh + 2 * 512 * 128, 256, bih + 1024, bhh + 1024, Bp2, bp2);

    feat0_kernel<<<(N * 128 + 255) / 256, 256, 0, stream>>>(features, W_in, b_in, feath, N);
    hist_kernel<<<(E + 255) / 256, 256, 0, stream>>>(dst, cnt, E);
    scan_kernel<<<1, 1024, 0, stream>>>(cnt, offs, cur, recip, N);
    scatter_kernel<<<(E + 255) / 256, 256, 0, stream>>>(src, dst, cur, esrc, E);

    const dim3 ggrid((N + BM - 1) / BM, 2, 1);
    const int gagg = (N + 15) / 16;
    const f16* featcur = feath;
    f16 *r0 = hA[0], *r1 = hA[1], *r2 = hA[2];   // read (old state)
    f16 *w0 = hB[0], *w1 = hB[1], *w2 = hB[2];   // write (new state)
    for (int step = 0; step < 11; ++step) {
        agg_kernel<<<gagg, 256, 0, stream>>>(featcur, offs, esrc, recip, aggh, N);
        gemm_lstm<3><<<ggrid, 256, 0, stream>>>(aggh, featcur, r0, Bp0, bp0, c0, w0, N);
        gemm_lstm<2><<<ggrid, 256, 0, stream>>>(w0, r1, nullptr, Bp1, bp1, c1, w1, N);
        gemm_lstm<2><<<ggrid, 256, 0, stream>>>(w1, r2, nullptr, Bp2, bp2, c2, w2, N);
        featcur = w2;
        f16* t;
        t = r0; r0 = w0; w0 = t;
        t = r1; r1 = w1; w1 = t;
        t = r2; r2 = w2; w2 = t;
    }
    out_kernel<<<N, 64, 0, stream>>>((const f16*)featcur, W_out, b_out, out);
}